// Round 7
// baseline (65.051 us; speedup 1.0000x reference)
//
#include <hip/hip_runtime.h>
#include <hip/hip_bf16.h>

#define NKVH 4
#define SEQ 4096
#define BLK 64
#define NW 8
#define NQB 64

typedef __attribute__((ext_vector_type(8))) short bf16x8;
typedef __attribute__((ext_vector_type(4))) float f32x4;

// round-half-up f32->bf16 pair pack: result = [bf16(hi)<<16 | bf16(lo)]
__device__ __forceinline__ unsigned pkbf(unsigned lo, unsigned hi) {
  return __builtin_amdgcn_perm(hi + 0x8000u, lo + 0x8000u, 0x07060302u);
}

// ---- pre-pass: K and V^T -> bf16 in MFMA-fragment-linear order ----
// K tile chunk o in [0,512): s=o>>8, f=(o>>6)&3, lg=(o>>4)&3, lr=o&15
//   holds K[f*16+lr][(s*4+lg)*8 .. +8)
// V tile chunk o: holds V^T[dt*16+lr][s*32+lg*8 .. +8)  (dt=(o>>6)&3)
__global__ __launch_bounds__(256, 2)
void prep_kernel(const float* __restrict__ kp, const float* __restrict__ vp,
                 short* __restrict__ kw, short* __restrict__ vt)
{
  const int ki = blockIdx.x, kvh = blockIdx.y, b = blockIdx.z;
  const size_t base = (((size_t)(b*NKVH + kvh)*SEQ) + (size_t)ki*BLK)*64;
  __shared__ float sk[64][72];
  __shared__ float sv[64][72];
  const int t = threadIdx.x;
  #pragma unroll
  for (int it = 0; it < 4; ++it) {
    const int i = t + it*256;            // 1024 float4 tasks per tensor
    const int row = i >> 4, c4 = i & 15;
    float4 a = *(const float4*)(kp + base + row*64 + c4*4);
    *(float4*)&sk[row][c4*4] = a;
    float4 v = *(const float4*)(vp + base + row*64 + c4*4);
    *(float4*)&sv[row][c4*4] = v;
  }
  __syncthreads();
  #pragma unroll
  for (int it = 0; it < 2; ++it) {
    const int o = t + it*256;
    const int s = o >> 8, fd = (o >> 6) & 3, lg = (o >> 4) & 3, lr = o & 15;
    const float* src = &sk[fd*16 + lr][(s*4 + lg)*8];
    uint4 w;
    w.x = pkbf(__float_as_uint(src[0]), __float_as_uint(src[1]));
    w.y = pkbf(__float_as_uint(src[2]), __float_as_uint(src[3]));
    w.z = pkbf(__float_as_uint(src[4]), __float_as_uint(src[5]));
    w.w = pkbf(__float_as_uint(src[6]), __float_as_uint(src[7]));
    *(uint4*)(kw + base + (size_t)o*8) = w;
    const int d = fd*16 + lr;
    const int n0 = s*32 + lg*8;
    uint4 u;
    u.x = pkbf(__float_as_uint(sv[n0+0][d]), __float_as_uint(sv[n0+1][d]));
    u.y = pkbf(__float_as_uint(sv[n0+2][d]), __float_as_uint(sv[n0+3][d]));
    u.z = pkbf(__float_as_uint(sv[n0+4][d]), __float_as_uint(sv[n0+5][d]));
    u.w = pkbf(__float_as_uint(sv[n0+6][d]), __float_as_uint(sv[n0+7][d]));
    *(uint4*)(vt + base + (size_t)o*8) = u;
  }
}

// ---- main: 1 head/wave, joint 2-window softmax, zero barriers ----
__global__ __launch_bounds__(256, 2)
void sattn_kernel(const float* __restrict__ qp, const short* __restrict__ kw,
                  const short* __restrict__ vt, const float* __restrict__ alibi,
                  const int* __restrict__ seg, const int* __restrict__ bidx,
                  float* __restrict__ outp)
{
  // 2048 blocks = 8 XCDs x 256; pin each (b,kvh) to one XCD's L2
  const int raw = blockIdx.x;
  const int xcd = raw & 7, li = raw >> 3;
  const int b = xcd >> 2, kvh = xcd & 3;
  const int qb = li & 63, g = li >> 6;
  const int head = kvh*4 + g;

  const int tid = threadIdx.x;
  const int wave = tid >> 6, lane = tid & 63;
  const int lr = lane & 15, lg = lane >> 4;

  __shared__ short plds[4][16][136];   // per-wave P (16 rows x 128 cols bf16)

  int kis[NW];
  #pragma unroll
  for (int i = 0; i < NW; ++i) kis[i] = bidx[qb*NW + i];

  const int m_glob = qb*BLK + wave*16 + lr;
  const int sq = seg[b*SEQ + m_glob];
  const float LOG2E = 1.4426950408889634f;
  const float nslope = -alibi[head] * LOG2E;

  // Q (scaled by 0.125*log2e) into registers, bf16
  bf16x8 qf[2];
  {
    const float qs = 0.125f * LOG2E;
    const float* qrow = qp + (((size_t)b*16 + head)*SEQ + m_glob)*64;
    #pragma unroll
    for (int s = 0; s < 2; ++s) {
      float4 a = *(const float4*)(qrow + s*32 + lg*8);
      float4 c = *(const float4*)(qrow + s*32 + lg*8 + 4);
      union { unsigned u[4]; bf16x8 v; } cv;
      cv.u[0] = pkbf(__float_as_uint(a.x*qs), __float_as_uint(a.y*qs));
      cv.u[1] = pkbf(__float_as_uint(a.z*qs), __float_as_uint(a.w*qs));
      cv.u[2] = pkbf(__float_as_uint(c.x*qs), __float_as_uint(c.y*qs));
      cv.u[3] = pkbf(__float_as_uint(c.z*qs), __float_as_uint(c.w*qs));
      qf[s] = cv.v;
    }
  }

  float mrun = -1e30f, lrun = 0.f;
  f32x4 oacc[4];
  #pragma unroll
  for (int dt = 0; dt < 4; ++dt) { f32x4 z = {0.f,0.f,0.f,0.f}; oacc[dt] = z; }

  const short* kbase = kw + ((size_t)(b*NKVH + kvh)*SEQ)*64;
  const short* vbase = vt + ((size_t)(b*NKVH + kvh)*SEQ)*64;
  const int segbase = b*SEQ;

  #pragma unroll
  for (int t2 = 0; t2 < 4; ++t2) {
    const int i0 = kis[2*t2], i1 = kis[2*t2 + 1];
    if (i1 < 0) continue;            // kis ascending: i1<0 => both invalid
    const int c0 = i0 < 0 ? 0 : i0;
    const short* kt0 = kbase + (size_t)c0*4096;
    const short* kt1 = kbase + (size_t)i1*4096;
    const short* vt0 = vbase + (size_t)c0*4096;
    const short* vt1 = vbase + (size_t)i1*4096;

    // ---- QK^T for both windows: 16 independent MFMAs ----
    f32x4 sacc[2][4];
    #pragma unroll
    for (int w = 0; w < 2; ++w)
      #pragma unroll
      for (int f = 0; f < 4; ++f) { f32x4 z = {0.f,0.f,0.f,0.f}; sacc[w][f] = z; }
    #pragma unroll
    for (int s = 0; s < 2; ++s) {
      bf16x8 k0[4], k1[4];
      #pragma unroll
      for (int f = 0; f < 4; ++f) {
        k0[f] = *(const bf16x8*)(kt0 + ((size_t)(s*256 + f*64 + lane))*8);
        k1[f] = *(const bf16x8*)(kt1 + ((size_t)(s*256 + f*64 + lane))*8);
      }
      #pragma unroll
      for (int f = 0; f < 4; ++f)
        sacc[0][f] = __builtin_amdgcn_mfma_f32_16x16x32_bf16(k0[f], qf[s], sacc[0][f], 0, 0, 0);
      #pragma unroll
      for (int f = 0; f < 4; ++f)
        sacc[1][f] = __builtin_amdgcn_mfma_f32_16x16x32_bf16(k1[f], qf[s], sacc[1][f], 0, 0, 0);
    }

    // ---- mask + ALiBi (dead -> huge pos_diff), joint row max over 128 cols ----
    float mblk = -3.0e38f;
    #pragma unroll
    for (int w = 0; w < 2; ++w) {
      const int ki = w ? i1 : c0;
      const bool wdead = (w == 0) && (i0 < 0);
      #pragma unroll
      for (int f = 0; f < 4; ++f) {
        const int4 sk4 = *(const int4*)(seg + segbase + ki*BLK + f*16 + lg*4);
        const int skr[4] = {sk4.x, sk4.y, sk4.z, sk4.w};
        #pragma unroll
        for (int r = 0; r < 4; ++r) {
          const int n_glob = ki*BLK + f*16 + lg*4 + r;
          const bool dead = wdead || (n_glob > m_glob) || (skr[r] != sq);
          const float pd = dead ? 3.0e34f : (float)(m_glob - n_glob);
          sacc[w][f][r] = fmaf(nslope, pd, sacc[w][f][r]);
          mblk = fmaxf(mblk, sacc[w][f][r]);
        }
      }
    }
    mblk = fmaxf(mblk, __shfl_xor(mblk, 16));
    mblk = fmaxf(mblk, __shfl_xor(mblk, 32));
    const float mnew = fmaxf(mrun, mblk);
    const float corr = __builtin_amdgcn_exp2f(mrun - mnew);
    mrun = mnew;

    // ---- single exp/pack pass over 128 cols ----
    float psum = 0.f;
    #pragma unroll
    for (int w = 0; w < 2; ++w)
      #pragma unroll
      for (int f = 0; f < 4; ++f)
        #pragma unroll
        for (int rp = 0; rp < 2; ++rp) {
          float p0 = __builtin_amdgcn_exp2f(sacc[w][f][2*rp]   - mnew);
          float p1 = __builtin_amdgcn_exp2f(sacc[w][f][2*rp+1] - mnew);
          psum += p0 + p1;
          *(unsigned*)&plds[wave][lr][w*64 + f*16 + lg*4 + 2*rp] =
              pkbf(__float_as_uint(p0), __float_as_uint(p1));
        }
    psum += __shfl_xor(psum, 16);
    psum += __shfl_xor(psum, 32);
    lrun = lrun*corr + psum;
    #pragma unroll
    for (int dt = 0; dt < 4; ++dt) oacc[dt] *= corr;

    // ---- PV over 128-deep K dimension (4 slices of 32) ----
    #pragma unroll
    for (int sl = 0; sl < 4; ++sl) {
      const short* vtt = (sl < 2) ? vt0 : vt1;
      const int s = sl & 1;
      bf16x8 pf = *(const bf16x8*)&plds[wave][lr][sl*32 + lg*8];
      #pragma unroll
      for (int dt = 0; dt < 4; ++dt) {
        bf16x8 vf = *(const bf16x8*)(vtt + ((size_t)(s*256 + dt*64 + lane))*8);
        oacc[dt] = __builtin_amdgcn_mfma_f32_16x16x32_bf16(vf, pf, oacc[dt], 0, 0, 0);
      }
    }
  }

  // ---- epilogue ----
  const float inv = lrun > 0.f ? 1.f/lrun : 0.f;
  float* dst = outp + (((size_t)b*16 + head)*SEQ + m_glob)*64;
  #pragma unroll
  for (int dt = 0; dt < 4; ++dt) {
    float4 o;
    o.x = oacc[dt][0]*inv; o.y = oacc[dt][1]*inv;
    o.z = oacc[dt][2]*inv; o.w = oacc[dt][3]*inv;
    *(float4*)&dst[dt*16 + lg*4] = o;
  }
}

extern "C" void kernel_launch(void* const* d_in, const int* in_sizes, int n_in,
                              void* d_out, int out_size, void* d_ws, size_t ws_size,
                              hipStream_t stream) {
  const float* q    = (const float*)d_in[0];
  const float* k    = (const float*)d_in[1];
  const float* v    = (const float*)d_in[2];
  const float* al   = (const float*)d_in[3];
  const int*   sg   = (const int*)d_in[4];
  const int*   bi   = (const int*)d_in[5];
  short* kws  = (short*)d_ws;                              // 4 MiB
  short* vtws = (short*)((char*)d_ws + (size_t)(1u<<22));  // 4 MiB
  dim3 pgrid(NQB, NKVH, 2);
  prep_kernel<<<pgrid, 256, 0, stream>>>(k, v, kws, vtws);
  sattn_kernel<<<dim3(2048), 256, 0, stream>>>(q, kws, vtws, al, sg, bi, (float*)d_out);
}

// Round 8
// 53.787 us; speedup vs baseline: 1.2094x; 1.2094x over previous
//
#include <hip/hip_runtime.h>
#include <hip/hip_bf16.h>

#define NKVH 4
#define SEQ 4096
#define BLK 64
#define NW 8
#define NQB 64

typedef __attribute__((ext_vector_type(8))) short bf16x8;
typedef __attribute__((ext_vector_type(4))) float f32x4;

// round-half-up f32->bf16 pair pack: result = [bf16(hi)<<16 | bf16(lo)]
__device__ __forceinline__ unsigned pkbf(unsigned lo, unsigned hi) {
  return __builtin_amdgcn_perm(hi + 0x8000u, lo + 0x8000u, 0x07060302u);
}

__device__ __forceinline__ void gload16(const void* g, void* l) {
  __builtin_amdgcn_global_load_lds(
      (const __attribute__((address_space(1))) void*)g,
      (__attribute__((address_space(3))) void*)l, 16, 0, 0);
}

// ---- pre-pass: K and V^T -> bf16 in MFMA-fragment-linear order ----
// K tile chunk o in [0,512): s=o>>8, f=(o>>6)&3, lg=(o>>4)&3, lr=o&15
//   holds K[f*16+lr][(s*4+lg)*8 .. +8)
// V tile chunk o: holds V^T[dt*16+lr][s*32+lg*8 .. +8)  (dt=(o>>6)&3)
__global__ __launch_bounds__(256, 2)
void prep_kernel(const float* __restrict__ kp, const float* __restrict__ vp,
                 short* __restrict__ kw, short* __restrict__ vt)
{
  const int ki = blockIdx.x, kvh = blockIdx.y, b = blockIdx.z;
  const size_t base = (((size_t)(b*NKVH + kvh)*SEQ) + (size_t)ki*BLK)*64;
  __shared__ float sk[64][72];
  __shared__ float sv[64][72];
  const int t = threadIdx.x;
  #pragma unroll
  for (int it = 0; it < 4; ++it) {
    const int i = t + it*256;            // 1024 float4 tasks per tensor
    const int row = i >> 4, c4 = i & 15;
    float4 a = *(const float4*)(kp + base + row*64 + c4*4);
    *(float4*)&sk[row][c4*4] = a;
    float4 v = *(const float4*)(vp + base + row*64 + c4*4);
    *(float4*)&sv[row][c4*4] = v;
  }
  __syncthreads();
  #pragma unroll
  for (int it = 0; it < 2; ++it) {
    const int o = t + it*256;
    const int s = o >> 8, fd = (o >> 6) & 3, lg = (o >> 4) & 3, lr = o & 15;
    const float* src = &sk[fd*16 + lr][(s*4 + lg)*8];
    uint4 w;
    w.x = pkbf(__float_as_uint(src[0]), __float_as_uint(src[1]));
    w.y = pkbf(__float_as_uint(src[2]), __float_as_uint(src[3]));
    w.z = pkbf(__float_as_uint(src[4]), __float_as_uint(src[5]));
    w.w = pkbf(__float_as_uint(src[6]), __float_as_uint(src[7]));
    *(uint4*)(kw + base + (size_t)o*8) = w;
    const int d = fd*16 + lr;
    const int n0 = s*32 + lg*8;
    uint4 u;
    u.x = pkbf(__float_as_uint(sv[n0+0][d]), __float_as_uint(sv[n0+1][d]));
    u.y = pkbf(__float_as_uint(sv[n0+2][d]), __float_as_uint(sv[n0+3][d]));
    u.z = pkbf(__float_as_uint(sv[n0+4][d]), __float_as_uint(sv[n0+5][d]));
    u.w = pkbf(__float_as_uint(sv[n0+6][d]), __float_as_uint(sv[n0+7][d]));
    *(uint4*)(vt + base + (size_t)o*8) = u;
  }
}

// ---- main: 8 waves (4 rowgroups x 2 heads), LDS-staged K/V via global_load_lds,
//      setprio MFMA, defer-max softmax, diagonal-only causal check ----
__global__ __launch_bounds__(512, 2)
void sattn_kernel(const float* __restrict__ qp, const short* __restrict__ kw,
                  const short* __restrict__ vt, const float* __restrict__ alibi,
                  const int* __restrict__ seg, const int* __restrict__ bidx,
                  float* __restrict__ outp)
{
  // 1024 blocks = 8 XCDs x 128; pin each (b,kvh) to one XCD's L2
  const int raw = blockIdx.x;
  const int xcd = raw & 7, li = raw >> 3;
  const int b = xcd >> 2, kvh = xcd & 3;
  const int qb = li & 63, hp = li >> 6;

  const int tid = threadIdx.x;
  const int wave = tid >> 6, lane = tid & 63;
  const int lr = lane & 15, lg = lane >> 4;
  const int wr = wave & 3, wh = wave >> 2;   // row-group, head-within-pair
  const int head = kvh*4 + hp*2 + wh;

  __shared__ short klds[2][4096];
  __shared__ short vlds[2][4096];
  __shared__ short plds[8][16][72];

  int kis[NW];
  #pragma unroll
  for (int i = 0; i < NW; ++i) kis[i] = bidx[qb*NW + i];

  const int m_glob = qb*BLK + wr*16 + lr;
  const int mloc = wr*16 + lr;
  const int sq = seg[b*SEQ + m_glob];
  const float LOG2E = 1.4426950408889634f;
  const float nslope = -alibi[head] * LOG2E;

  const short* kbase = kw + ((size_t)(b*NKVH + kvh)*SEQ)*64;
  const short* vbase = vt + ((size_t)(b*NKVH + kvh)*SEQ)*64;

  auto STAGE = [&](int buf, int wi) {
    const int ki = kis[wi] < 0 ? 0 : kis[wi];
    gload16((const char*)(kbase + (size_t)ki*4096) + tid*16,
            (char*)&klds[buf][0] + wave*1024);
    gload16((const char*)(vbase + (size_t)ki*4096) + tid*16,
            (char*)&vlds[buf][0] + wave*1024);
  };

  STAGE(0, 0);

  // Q (scaled by 0.125*log2e) into registers, bf16
  bf16x8 qf[2];
  {
    const float qs = 0.125f * LOG2E;
    const float* qrow = qp + (((size_t)b*16 + head)*SEQ + m_glob)*64;
    #pragma unroll
    for (int s = 0; s < 2; ++s) {
      float4 a = *(const float4*)(qrow + s*32 + lg*8);
      float4 c = *(const float4*)(qrow + s*32 + lg*8 + 4);
      union { unsigned u[4]; bf16x8 v; } cv;
      cv.u[0] = pkbf(__float_as_uint(a.x*qs), __float_as_uint(a.y*qs));
      cv.u[1] = pkbf(__float_as_uint(a.z*qs), __float_as_uint(a.w*qs));
      cv.u[2] = pkbf(__float_as_uint(c.x*qs), __float_as_uint(c.y*qs));
      cv.u[3] = pkbf(__float_as_uint(c.z*qs), __float_as_uint(c.w*qs));
      qf[s] = cv.v;
    }
  }

  float mrun = -1e30f, lrun = 0.f;
  f32x4 oacc[4];
  #pragma unroll
  for (int dt = 0; dt < 4; ++dt) { f32x4 z = {0.f,0.f,0.f,0.f}; oacc[dt] = z; }

  __syncthreads();   // buf0 staged

  int cur = 0;
  #pragma unroll
  for (int wi = 0; wi < NW; ++wi) {
    if (wi + 1 < NW) STAGE(cur ^ 1, wi + 1);   // loads fly during compute
    const int ki = kis[wi];
    if (ki >= 0) {
      // segment ids for this window (L1-hot, shared across waves)
      int skr[4][4];
      #pragma unroll
      for (int f = 0; f < 4; ++f) {
        const int4 s4 = *(const int4*)(seg + b*SEQ + ki*BLK + f*16 + lg*4);
        skr[f][0] = s4.x; skr[f][1] = s4.y; skr[f][2] = s4.z; skr[f][3] = s4.w;
      }

      // ---- QK^T ----
      f32x4 sacc[4];
      #pragma unroll
      for (int f = 0; f < 4; ++f) { f32x4 z = {0.f,0.f,0.f,0.f}; sacc[f] = z; }
      #pragma unroll
      for (int s = 0; s < 2; ++s) {
        bf16x8 kf[4];
        #pragma unroll
        for (int f = 0; f < 4; ++f)
          kf[f] = *(const bf16x8*)&klds[cur][(s*256 + f*64 + lane)*8];
        __builtin_amdgcn_s_setprio(1);
        #pragma unroll
        for (int f = 0; f < 4; ++f)
          sacc[f] = __builtin_amdgcn_mfma_f32_16x16x32_bf16(kf[f], qf[s], sacc[f], 0, 0, 0);
        __builtin_amdgcn_s_setprio(0);
      }

      // ---- mask + ALiBi; causal check only on the diagonal window ----
      const float fdmb = (float)(m_glob - ki*BLK - lg*4);
      float mblk = -3.0e38f;
      #pragma unroll
      for (int f = 0; f < 4; ++f)
        #pragma unroll
        for (int r = 0; r < 4; ++r) {
          bool dead = (skr[f][r] != sq);
          if (wi == NW-1) dead = dead || ((f*16 + lg*4 + r) > mloc);
          const float pd = dead ? 3.0e34f : (fdmb - (float)(f*16 + r));
          sacc[f][r] = fmaf(nslope, pd, sacc[f][r]);
          mblk = fmaxf(mblk, sacc[f][r]);
        }
      mblk = fmaxf(mblk, __shfl_xor(mblk, 16));
      mblk = fmaxf(mblk, __shfl_xor(mblk, 32));

      // defer-max: skip rescale when max growth small (exp headroom 2^8)
      float mexp = mrun;
      if (!__all(mblk <= mrun + 8.f)) {
        const float mnew = fmaxf(mrun, mblk);
        const float corr = __builtin_amdgcn_exp2f(mrun - mnew);
        lrun *= corr;
        #pragma unroll
        for (int dt = 0; dt < 4; ++dt) oacc[dt] *= corr;
        mrun = mnew;
        mexp = mnew;
      }

      float psum = 0.f;
      #pragma unroll
      for (int f = 0; f < 4; ++f)
        #pragma unroll
        for (int rp = 0; rp < 2; ++rp) {
          float p0 = __builtin_amdgcn_exp2f(sacc[f][2*rp]   - mexp);
          float p1 = __builtin_amdgcn_exp2f(sacc[f][2*rp+1] - mexp);
          psum += p0 + p1;
          *(unsigned*)&plds[wave][lr][f*16 + lg*4 + 2*rp] =
              pkbf(__float_as_uint(p0), __float_as_uint(p1));
        }
      psum += __shfl_xor(psum, 16);
      psum += __shfl_xor(psum, 32);
      lrun += psum;

      // ---- PV ----
      #pragma unroll
      for (int s = 0; s < 2; ++s) {
        bf16x8 pf = *(const bf16x8*)&plds[wave][lr][s*32 + lg*8];
        bf16x8 vf[4];
        #pragma unroll
        for (int dt = 0; dt < 4; ++dt)
          vf[dt] = *(const bf16x8*)&vlds[cur][(s*256 + dt*64 + lane)*8];
        __builtin_amdgcn_s_setprio(1);
        #pragma unroll
        for (int dt = 0; dt < 4; ++dt)
          oacc[dt] = __builtin_amdgcn_mfma_f32_16x16x32_bf16(vf[dt], pf, oacc[dt], 0, 0, 0);
        __builtin_amdgcn_s_setprio(0);
      }
    }
    __syncthreads();
    cur ^= 1;
  }

  // ---- epilogue ----
  const float inv = lrun > 0.f ? 1.f/lrun : 0.f;
  float* dst = outp + (((size_t)b*16 + head)*SEQ + m_glob)*64;
  #pragma unroll
  for (int dt = 0; dt < 4; ++dt) {
    float4 o;
    o.x = oacc[dt][0]*inv; o.y = oacc[dt][1]*inv;
    o.z = oacc[dt][2]*inv; o.w = oacc[dt][3]*inv;
    *(float4*)&dst[dt*16 + lg*4] = o;
  }
}

extern "C" void kernel_launch(void* const* d_in, const int* in_sizes, int n_in,
                              void* d_out, int out_size, void* d_ws, size_t ws_size,
                              hipStream_t stream) {
  const float* q    = (const float*)d_in[0];
  const float* k    = (const float*)d_in[1];
  const float* v    = (const float*)d_in[2];
  const float* al   = (const float*)d_in[3];
  const int*   sg   = (const int*)d_in[4];
  const int*   bi   = (const int*)d_in[5];
  short* kws  = (short*)d_ws;                              // 4 MiB
  short* vtws = (short*)((char*)d_ws + (size_t)(1u<<22));  // 4 MiB
  dim3 pgrid(NQB, NKVH, 2);
  prep_kernel<<<pgrid, 256, 0, stream>>>(k, v, kws, vtws);
  sattn_kernel<<<dim3(1024), 512, 0, stream>>>(q, kws, vtws, al, sg, bi, (float*)d_out);
}